// Round 1
// baseline (331.538 us; speedup 1.0000x reference)
//
#include <hip/hip_runtime.h>

#define NROW 8192
#define INF  512
#define OUTF 256

typedef __bf16 v8bf __attribute__((ext_vector_type(8)));
typedef __bf16 v4bf __attribute__((ext_vector_type(4)));
typedef float  v4f  __attribute__((ext_vector_type(4)));

__device__ __forceinline__ v8bf cvt_bf8(v4f u0, v4f u1) {
  v8bf v;
  v[0]=(__bf16)u0[0]; v[1]=(__bf16)u0[1]; v[2]=(__bf16)u0[2]; v[3]=(__bf16)u0[3];
  v[4]=(__bf16)u1[0]; v[5]=(__bf16)u1[1]; v[6]=(__bf16)u1[2]; v[7]=(__bf16)u1[3];
  return v;
}

// ---------------------------------------------------------------------------
// Kernel A: seq = feat @ W^T  (bf16 MFMA, f32 inputs converted on the fly)
// Output stored bf16 in MFMA-B-fragment-packed layout:
//   elem(m,o) -> (((m>>5)*16 + (o>>4))*64 + ((m>>3)&3)*16 + (o&15))*8 + (m&7)
// so kernel B's b-frag is one coalesced dwordx4 per lane.
// ---------------------------------------------------------------------------
__global__ __launch_bounds__(256) void seq_fts_kernel(
    const float* __restrict__ feat, const float* __restrict__ W,
    __bf16* __restrict__ Bp) {
  const int tid  = threadIdx.x;
  const int lane = tid & 63, w = tid >> 6;
  const int llo  = lane & 15, lhi = lane >> 4;
  const int row0 = blockIdx.x * 64;
  const int col0 = w * 64;

  v4f acc[4][4] = {};
#pragma unroll 1
  for (int kb = 0; kb < INF / 32; ++kb) {
    const int kofs = kb * 32 + lhi * 8;
    v8bf a[4], b[4];
#pragma unroll
    for (int i = 0; i < 4; ++i) {
      const float* p = feat + (size_t)(row0 + i * 16 + llo) * INF + kofs;
      a[i] = cvt_bf8(*(const v4f*)p, *(const v4f*)(p + 4));
    }
#pragma unroll
    for (int i = 0; i < 4; ++i) {
      const float* p = W + (size_t)(col0 + i * 16 + llo) * INF + kofs;
      b[i] = cvt_bf8(*(const v4f*)p, *(const v4f*)(p + 4));
    }
#pragma unroll
    for (int ri = 0; ri < 4; ++ri)
#pragma unroll
      for (int ci = 0; ci < 4; ++ci)
        acc[ri][ci] = __builtin_amdgcn_mfma_f32_16x16x32_bf16(
            a[ri], b[ci], acc[ri][ci], 0, 0, 0);
  }
  // C/D layout: row = (lane>>4)*4 + r, col = lane&15  (verified m89/m91)
#pragma unroll
  for (int ri = 0; ri < 4; ++ri)
#pragma unroll
    for (int ci = 0; ci < 4; ++ci) {
      const int mf = row0 + ri * 16 + lhi * 4;   // first of 4 consecutive rows
      const int o  = col0 + ci * 16 + llo;
      size_t e = (((size_t)(mf >> 5) * 16 + (o >> 4)) * 64 +
                  ((mf >> 3) & 3) * 16 + (o & 15)) * 8 + (mf & 7);
      v4bf v;
      v[0] = (__bf16)acc[ri][ci][0]; v[1] = (__bf16)acc[ri][ci][1];
      v[2] = (__bf16)acc[ri][ci][2]; v[3] = (__bf16)acc[ri][ci][3];
      *(v4bf*)(Bp + e) = v;   // 8B store, j-contiguous (mf&3 == 0)
    }
}

// ---------------------------------------------------------------------------
// Kernel B: out = prelu(adj @ seq + bias), one 64-row strip per block.
// adj tile (64x64 f32) staged via global_load_lds into double-buffered LDS;
// LDS layout XOR-swizzled via pre-swizzled SOURCE addresses (m173 pattern):
//   elem(r,k) at byte r*256 + ((k>>2) ^ (r&15))*16 + (k&3)*4
// b-frags read directly from packed seq (L2-resident, 4 MB).
// ---------------------------------------------------------------------------
__global__ __launch_bounds__(256) void gcn_agg_kernel(
    const float* __restrict__ adjA, const float* __restrict__ adjB,
    const __bf16* __restrict__ Bp, const float* __restrict__ bias,
    const float* __restrict__ prelu_a, float* __restrict__ out) {
  const int tid  = threadIdx.x;
  const int lane = tid & 63, w = tid >> 6;
  const int llo  = lane & 15, lhi = lane >> 4;
  const int row0 = blockIdx.x * 64;
  const int wc0  = w * 64;
  const float* __restrict__ adj = blockIdx.y ? adjB : adjA;
  float* __restrict__ outp = out + (size_t)blockIdx.y * NROW * OUTF;

  __shared__ float Abuf[2][64 * 64];

  v4f acc[4][4] = {};

  // wave w stages rows [w*16, w*16+16): 4 x global_load_lds(16B/lane)
  auto stage = [&](int buf, int kb) {
#pragma unroll
    for (int i = 0; i < 4; ++i) {
      const int row = w * 16 + i * 4 + lhi;          // tile-local row
      const int k4  = llo ^ (i * 4 + lhi);           // pre-swizzled source slot
      const float* src = adj + (size_t)(row0 + row) * NROW + kb * 64 + k4 * 4;
      char* lds = (char*)(&Abuf[buf][0]) + (w * 4 + i) * 1024; // wave-uniform
      __builtin_amdgcn_global_load_lds(
          (const __attribute__((address_space(1))) void*)src,
          (__attribute__((address_space(3))) void*)lds, 16, 0, 0);
    }
  };

  auto read_a = [&](int buf, int ri, int s) -> v8bf {
    const int row  = ri * 16 + llo;                  // row & 15 == llo
    const int k4a  = s * 8 + lhi * 2;
    const char* base = (const char*)(&Abuf[buf][0]) + row * 256;
    v4f u0 = *(const v4f*)(base + (((k4a    ) ^ llo) << 4));
    v4f u1 = *(const v4f*)(base + (((k4a + 1) ^ llo) << 4));
    return cvt_bf8(u0, u1);
  };

  stage(0, 0);
  asm volatile("s_waitcnt vmcnt(0)" ::: "memory");
  __syncthreads();

#pragma unroll 1
  for (int kb = 0; kb < NROW / 64; ++kb) {
    const int cur = kb & 1;
    if (kb + 1 < NROW / 64) stage(cur ^ 1, kb + 1);  // prefetch next tile
#pragma unroll
    for (int s = 0; s < 2; ++s) {
      v8bf a[4];
#pragma unroll
      for (int ri = 0; ri < 4; ++ri) a[ri] = read_a(cur, ri, s);
      const int kk = kb * 2 + s;
#pragma unroll
      for (int ci = 0; ci < 4; ++ci) {
        const __bf16* bsrc =
            Bp + (((size_t)kk * 16 + (w * 4 + ci)) * 64 + lane) * 8;
        v8bf b = *(const v8bf*)bsrc;
#pragma unroll
        for (int ri = 0; ri < 4; ++ri)
          acc[ri][ci] = __builtin_amdgcn_mfma_f32_16x16x32_bf16(
              a[ri], b, acc[ri][ci], 0, 0, 0);
      }
    }
    asm volatile("s_waitcnt vmcnt(0)" ::: "memory"); // next tile landed
    __syncthreads();
  }

  const float slope = prelu_a[0];
#pragma unroll
  for (int ci = 0; ci < 4; ++ci) {
    const int o  = wc0 + ci * 16 + llo;
    const float bs = bias[o];
#pragma unroll
    for (int ri = 0; ri < 4; ++ri) {
      const int m = row0 + ri * 16 + lhi * 4;
#pragma unroll
      for (int r = 0; r < 4; ++r) {
        float v = acc[ri][ci][r] + bs;
        outp[(size_t)(m + r) * OUTF + o] = v >= 0.f ? v : slope * v;
      }
    }
  }
}

extern "C" void kernel_launch(void* const* d_in, const int* in_sizes, int n_in,
                              void* d_out, int out_size, void* d_ws, size_t ws_size,
                              hipStream_t stream) {
  const float* feat = (const float*)d_in[0];
  const float* adj  = (const float*)d_in[1];
  const float* aug  = (const float*)d_in[2];
  const float* W    = (const float*)d_in[3];
  const float* bias = (const float*)d_in[4];
  const float* pa   = (const float*)d_in[5];
  float* out = (float*)d_out;
  __bf16* Bp = (__bf16*)d_ws;  // 8192*256 bf16 = 4 MB packed seq_fts

  seq_fts_kernel<<<dim3(NROW / 64), 256, 0, stream>>>(feat, W, Bp);
  gcn_agg_kernel<<<dim3(NROW / 64, 2), 256, 0, stream>>>(adj, aug, Bp, bias, pa, out);
}

// Round 2
// 234.714 us; speedup vs baseline: 1.4125x; 1.4125x over previous
//
#include <hip/hip_runtime.h>

#define NROW 8192
#define INF  512
#define OUTF 256
#define NT   (NROW / 64)   // 128 K-tiles

typedef __bf16 v8bf __attribute__((ext_vector_type(8)));
typedef __bf16 v4bf __attribute__((ext_vector_type(4)));
typedef float  v4f  __attribute__((ext_vector_type(4)));

__device__ __forceinline__ v8bf cvt_bf8(v4f u0, v4f u1) {
  v8bf v;
  v[0]=(__bf16)u0[0]; v[1]=(__bf16)u0[1]; v[2]=(__bf16)u0[2]; v[3]=(__bf16)u0[3];
  v[4]=(__bf16)u1[0]; v[5]=(__bf16)u1[1]; v[6]=(__bf16)u1[2]; v[7]=(__bf16)u1[3];
  return v;
}

// ---------------------------------------------------------------------------
// Kernel A: seq = feat @ W^T  (bf16 MFMA, f32 inputs converted on the fly)
// Output stored bf16 in MFMA-B-fragment-packed layout:
//   elem(m,o) -> (((m>>5)*16 + (o>>4))*64 + ((m>>3)&3)*16 + (o&15))*8 + (m&7)
// so kernel B's b-frag is one coalesced dwordx4 per lane.
// ---------------------------------------------------------------------------
__global__ __launch_bounds__(256) void seq_fts_kernel(
    const float* __restrict__ feat, const float* __restrict__ W,
    __bf16* __restrict__ Bp) {
  const int tid  = threadIdx.x;
  const int lane = tid & 63, w = tid >> 6;
  const int llo  = lane & 15, lhi = lane >> 4;
  const int row0 = blockIdx.x * 64;
  const int col0 = w * 64;

  v4f acc[4][4] = {};
#pragma unroll 1
  for (int kb = 0; kb < INF / 32; ++kb) {
    const int kofs = kb * 32 + lhi * 8;
    v8bf a[4], b[4];
#pragma unroll
    for (int i = 0; i < 4; ++i) {
      const float* p = feat + (size_t)(row0 + i * 16 + llo) * INF + kofs;
      a[i] = cvt_bf8(*(const v4f*)p, *(const v4f*)(p + 4));
    }
#pragma unroll
    for (int i = 0; i < 4; ++i) {
      const float* p = W + (size_t)(col0 + i * 16 + llo) * INF + kofs;
      b[i] = cvt_bf8(*(const v4f*)p, *(const v4f*)(p + 4));
    }
#pragma unroll
    for (int ri = 0; ri < 4; ++ri)
#pragma unroll
      for (int ci = 0; ci < 4; ++ci)
        acc[ri][ci] = __builtin_amdgcn_mfma_f32_16x16x32_bf16(
            a[ri], b[ci], acc[ri][ci], 0, 0, 0);
  }
#pragma unroll
  for (int ri = 0; ri < 4; ++ri)
#pragma unroll
    for (int ci = 0; ci < 4; ++ci) {
      const int mf = row0 + ri * 16 + lhi * 4;
      const int o  = col0 + ci * 16 + llo;
      size_t e = (((size_t)(mf >> 5) * 16 + (o >> 4)) * 64 +
                  ((mf >> 3) & 3) * 16 + (o & 15)) * 8 + (mf & 7);
      v4bf v;
      v[0] = (__bf16)acc[ri][ci][0]; v[1] = (__bf16)acc[ri][ci][1];
      v[2] = (__bf16)acc[ri][ci][2]; v[3] = (__bf16)acc[ri][ci][3];
      *(v4bf*)(Bp + e) = v;
    }
}

// ---------------------------------------------------------------------------
// Kernel B: out = prelu(adj @ seq + bias), one 64-row strip per block.
// A-tiles (64x64 f32) staged via global_load_lds, 3-deep LDS pipeline (48 KB),
// XOR-swizzled via pre-swizzled SOURCE addresses; counted vmcnt(12) waits
// (never 0 in steady state), raw s_barrier (no implicit vmcnt drain).
// B-fragments double-buffered in REGISTERS, issued BEFORE the A-stage each
// iteration so the in-order vmcnt FIFO never forces an A-pipeline drain.
// ---------------------------------------------------------------------------
__global__ __launch_bounds__(256) void gcn_agg_kernel(
    const float* __restrict__ adjA, const float* __restrict__ adjB,
    const __bf16* __restrict__ Bp, const float* __restrict__ bias,
    const float* __restrict__ prelu_a, float* __restrict__ out) {
  const int tid  = threadIdx.x;
  const int lane = tid & 63, w = tid >> 6;
  const int llo  = lane & 15, lhi = lane >> 4;
  const int row0 = blockIdx.x * 64;
  const int wc0  = w * 64;
  const float* __restrict__ adj = blockIdx.y ? adjB : adjA;
  float* __restrict__ outp = out + (size_t)blockIdx.y * NROW * OUTF;

  __shared__ float Abuf[3][64 * 64];   // 48 KB

  v4f acc[4][4] = {};

  // wave w stages rows [w*16, w*16+16): 4 x global_load_lds(16B/lane)
  auto stage = [&](int buf, int kb) {
#pragma unroll
    for (int i = 0; i < 4; ++i) {
      const int row = w * 16 + i * 4 + lhi;
      const int k4  = llo ^ (i * 4 + lhi);           // pre-swizzled source slot
      const float* src = adj + (size_t)(row0 + row) * NROW + kb * 64 + k4 * 4;
      char* lds = (char*)(&Abuf[buf][0]) + (w * 4 + i) * 1024;
      __builtin_amdgcn_global_load_lds(
          (const __attribute__((address_space(1))) void*)src,
          (__attribute__((address_space(3))) void*)lds, 16, 0, 0);
    }
  };

  auto read_a = [&](int buf, int ri, int s) -> v8bf {
    const int row  = ri * 16 + llo;                  // row & 15 == llo
    const int k4a  = s * 8 + lhi * 2;
    const char* base = (const char*)(&Abuf[buf][0]) + row * 256;
    v4f u0 = *(const v4f*)(base + (((k4a    ) ^ llo) << 4));
    v4f u1 = *(const v4f*)(base + (((k4a + 1) ^ llo) << 4));
    return cvt_bf8(u0, u1);
  };

  // B-fragment register loads: 8 x dwordx4 from packed, L2-resident Bp.
  const __bf16* __restrict__ Bpw = Bp + ((size_t)w * 4 * 64 + lane) * 8;
  auto load_b = [&](int kb, v8bf (&b)[8]) {
#pragma unroll
    for (int s = 0; s < 2; ++s)
#pragma unroll
      for (int ci = 0; ci < 4; ++ci)
        b[s * 4 + ci] =
            *(const v8bf*)(Bpw + ((size_t)(kb * 2 + s) * 16 + ci) * 512);
  };

  v8bf bA[8], bB[8];
  stage(0, 0);
  stage(1, 1);
  load_b(0, bA);

  // one iteration of the pipelined K-loop
  auto body = [&](int kb, v8bf (&bc)[8], v8bf (&bn)[8]) {
    const int cur = kb % 3;
    // counted wait: tile kb's A-stage retired; tile kb+1 A (4) + B(kb) regs
    // already consumed; B(kb+1-issue) not yet issued. 12 = 4 (A kb+1) + 8 (B kb).
    if (kb < NT - 1) asm volatile("s_waitcnt vmcnt(12)" ::: "memory");
    else             asm volatile("s_waitcnt vmcnt(8)"  ::: "memory");
    asm volatile("s_waitcnt lgkmcnt(0)" ::: "memory");
    __builtin_amdgcn_s_barrier();
    __builtin_amdgcn_sched_barrier(0);
    if (kb + 1 < NT) load_b(kb + 1, bn);          // issue B first (FIFO order!)
    if (kb + 2 < NT) stage((kb + 2) % 3, kb + 2); // then next A-tile
#pragma unroll
    for (int s = 0; s < 2; ++s) {
      v8bf a[4];
#pragma unroll
      for (int ri = 0; ri < 4; ++ri) a[ri] = read_a(cur, ri, s);
#pragma unroll
      for (int ci = 0; ci < 4; ++ci)
#pragma unroll
        for (int ri = 0; ri < 4; ++ri)
          acc[ri][ci] = __builtin_amdgcn_mfma_f32_16x16x32_bf16(
              a[ri], bc[s * 4 + ci], acc[ri][ci], 0, 0, 0);
    }
  };

#pragma unroll 1
  for (int kb = 0; kb < NT; kb += 2) {
    body(kb, bA, bB);
    body(kb + 1, bB, bA);
  }

  const float slope = prelu_a[0];
#pragma unroll
  for (int ci = 0; ci < 4; ++ci) {
    const int o  = wc0 + ci * 16 + llo;
    const float bs = bias[o];
#pragma unroll
    for (int ri = 0; ri < 4; ++ri) {
      const int m = row0 + ri * 16 + lhi * 4;
#pragma unroll
      for (int r = 0; r < 4; ++r) {
        float v = acc[ri][ci][r] + bs;
        outp[(size_t)(m + r) * OUTF + o] = v >= 0.f ? v : slope * v;
      }
    }
  }
}

extern "C" void kernel_launch(void* const* d_in, const int* in_sizes, int n_in,
                              void* d_out, int out_size, void* d_ws, size_t ws_size,
                              hipStream_t stream) {
  const float* feat = (const float*)d_in[0];
  const float* adj  = (const float*)d_in[1];
  const float* aug  = (const float*)d_in[2];
  const float* W    = (const float*)d_in[3];
  const float* bias = (const float*)d_in[4];
  const float* pa   = (const float*)d_in[5];
  float* out = (float*)d_out;
  __bf16* Bp = (__bf16*)d_ws;  // 8192*256 bf16 = 4 MB packed seq_fts

  seq_fts_kernel<<<dim3(NROW / 64), 256, 0, stream>>>(feat, W, Bp);
  gcn_agg_kernel<<<dim3(NROW / 64, 2), 256, 0, stream>>>(adj, aug, Bp, bias, pa, out);
}